// Round 8
// baseline (141.102 us; speedup 1.0000x reference)
//
#include <hip/hip_runtime.h>
#include <hip/hip_bf16.h>

// Problem dims (fixed by setup_inputs): B=16, A=9, H=56, W=56, N=64.
// Output: (B, A*H*W, N) fp32 IoU matrix, 115.6 MB.
//
// R7: chip-wide sweeping store order (HBM row-locality experiment).
//   7056 wave-slots (1764 blocks x 4 waves, all co-resident as R6).
//   Work unit = 1KB = 4 output rows. Unit u = j*7056 + s  (iter j, slot s).
//   4*7056 = 28224 = P  =>  iteration j covers EXACTLY batch j's output,
//   so at any instant the whole chip writes one contiguous ~7MB window
//   that sweeps through the 115.6MB output in 16 steps (fill-like order),
//   instead of 1764 independent 16KB streams (R6) that thrash HBM rows.
//   Decode: lane L pre-decodes batch (L>>2), local proposal 4s+(L&3) --
//   one decode, 2 exps per lane for the whole kernel (same as R6).
//   Iter j: shfl boxes from lanes 4j..4j+3; bboxes of batch j reloaded as
//   5 aligned float4 loads (20KB total set -> L1-resident after iter 0).

constexpr int B_ = 16;
constexpr int A_ = 9;
constexpr int H_ = 56;
constexpr int W_ = 56;
constexpr int N_ = 64;
constexpr int HW_ = H_ * W_;            // 3136
constexpr int P_ = A_ * HW_;            // 28224 proposals per batch
constexpr int NSLOTS = P_ / 4;          // 7056 wave-slots
constexpr int BLOCK = 256;
constexpr int NBLOCKS = NSLOTS * 64 / BLOCK;   // 1764

typedef float floatx4 __attribute__((ext_vector_type(4)));

__global__ __launch_bounds__(BLOCK, 7) void ssd_iou_kernel(
    const float* __restrict__ anc,      // (A,2)
    const float* __restrict__ grid,     // (B,H,W,2)
    const float* __restrict__ offsets,  // (B,A,H,W,4)
    const float* __restrict__ bboxes,   // (B,N,5)
    float* __restrict__ out)            // (B, P, N)
{
    const int t    = blockIdx.x * BLOCK + threadIdx.x;
    const int s    = t >> 6;            // wave-slot, 0..7055
    const int lane = t & 63;

    // ---- pre-decode: lane L owns batch (L>>2), local proposal 4s+(L&3) ----
    const int bl = lane >> 2;                   // batch this lane decodes
    const int lp = 4 * s + (lane & 3);          // local proposal in that batch
    const int a  = lp / HW_;
    const int hw = lp - a * HW_;

    const float4 off = reinterpret_cast<const float4*>(offsets)[bl * P_ + lp];
    const float2 g   = reinterpret_cast<const float2*>(grid)[bl * HW_ + hw];
    const float  aw  = anc[2 * a + 0];
    const float  ah  = anc[2 * a + 1];

    const float xc = g.x + off.x;
    const float yc = g.y + off.y;
    const float wp = aw * __expf(off.z);
    const float hp = ah * __expf(off.w);

    const float mx0 = xc - 0.5f * wp;   // this lane's decoded box
    const float my0 = yc - 0.5f * hp;
    const float mx1 = xc + 0.5f * wp;
    const float my1 = yc + 0.5f * hp;

    const int q   = lane >> 4;          // row within the 4-row unit
    const int g16 = lane & 15;          // bbox group: boxes 4g16..4g16+3

    // out float index for unit u = j*NSLOTS+s, row q, cols 4g16..:
    //   (j*P_ + 4s + q)*64 + 4*g16  =  j*(NSLOTS*256) + s*256 + q*64 + 4*g16
    float* obase = out + (size_t)s * 256 + q * 64 + 4 * g16;

    #pragma unroll 4
    for (int j = 0; j < B_; ++j) {
        // ---- batch j's bboxes 4g16..4g16+3: 20 floats, 5 aligned float4 ----
        const float4* bp =
            reinterpret_cast<const float4*>(bboxes + j * (N_ * 5) + 20 * g16);
        const float4 w0 = bp[0];
        const float4 w1 = bp[1];
        const float4 w2 = bp[2];
        const float4 w3 = bp[3];
        const float4 w4 = bp[4];
        // box k = flat floats [5k..5k+3]
        const float bx0[4] = { w0.x, w1.y, w2.z, w3.w };
        const float by0[4] = { w0.y, w1.z, w2.w, w4.x };
        const float bx1[4] = { w0.z, w1.w, w3.x, w4.y };
        const float by1[4] = { w0.w, w2.x, w3.y, w4.z };

        // ---- proposal box for (batch j, local 4s+q): held by lane 4j+q ----
        const int src = 4 * j + q;
        const float px0 = __shfl(mx0, src);
        const float py0 = __shfl(my0, src);
        const float px1 = __shfl(mx1, src);
        const float py1 = __shfl(my1, src);
        const float aop = (px1 - px0) * (py1 - py0);

        floatx4 res;
        #pragma unroll
        for (int k = 0; k < 4; ++k) {
            const float tlx = fmaxf(px0, bx0[k]);
            const float tly = fmaxf(py0, by0[k]);
            const float brx = fminf(px1, bx1[k]);
            const float bry = fminf(py1, by1[k]);

            const float iw  = fmaxf(brx - tlx, 0.0f);
            const float ih  = fmaxf(bry - tly, 0.0f);
            const float aoi = iw * ih;

            const float aob   = (bx1[k] - bx0[k]) * (by1[k] - by0[k]);
            const float denom = aop + aob - aoi;
            res[k] = aoi * __builtin_amdgcn_rcpf(denom);
        }

        *reinterpret_cast<floatx4*>(obase + (size_t)j * (NSLOTS * 256)) = res;
    }
}

extern "C" void kernel_launch(void* const* d_in, const int* in_sizes, int n_in,
                              void* d_out, int out_size, void* d_ws, size_t ws_size,
                              hipStream_t stream) {
    const float* anc     = (const float*)d_in[0];
    const float* grid    = (const float*)d_in[1];
    const float* offsets = (const float*)d_in[2];
    const float* bboxes  = (const float*)d_in[3];
    float* out = (float*)d_out;

    ssd_iou_kernel<<<NBLOCKS, BLOCK, 0, stream>>>(anc, grid, offsets, bboxes, out);
}